// Round 11
// baseline (314.640 us; speedup 1.0000x reference)
//
#include <hip/hip_runtime.h>

#define N_NODES 16384
#define N_EDGES 524288

typedef _Float16 half8v __attribute__((ext_vector_type(8)));
typedef _Float16 half4v __attribute__((ext_vector_type(4)));
typedef float floatx16 __attribute__((ext_vector_type(16)));
typedef float floatx4 __attribute__((ext_vector_type(4)));

#define MFMA16(a, b, c) __builtin_amdgcn_mfma_f32_32x32x16_f16(a, b, c, 0, 0, 0)

// ---------------- fused CSR-hist + f16 prep ----------------

__global__ __launch_bounds__(256) void hist_prep_kernel(const int* __restrict__ dst,
                                                        int* __restrict__ deg,
                                                        const float* __restrict__ x,
                                                        _Float16* __restrict__ xh,
                                                        const float* __restrict__ Wl1,
                                                        const float* __restrict__ Wr1,
                                                        const float* __restrict__ Wl2,
                                                        const float* __restrict__ Wr2,
                                                        const float* __restrict__ Wlin,
                                                        _Float16* __restrict__ Wl1t,
                                                        _Float16* __restrict__ Wr1t,
                                                        _Float16* __restrict__ Wl2t,
                                                        _Float16* __restrict__ Wr2t,
                                                        _Float16* __restrict__ Wlint) {
  int b = blockIdx.x, t = threadIdx.x;
  if (b < 2048) {
    int e = b * 256 + t;
    atomicAdd(&deg[dst[e]], 1);
  } else if (b < 3072) {
    int bb = b - 2048;
    size_t base = (size_t)bb * 2048 + t * 8;
    float4 v0 = *(const float4*)&x[base];
    float4 v1 = *(const float4*)&x[base + 4];
    half8v h;
    h[0] = (_Float16)v0.x; h[1] = (_Float16)v0.y;
    h[2] = (_Float16)v0.z; h[3] = (_Float16)v0.w;
    h[4] = (_Float16)v1.x; h[5] = (_Float16)v1.y;
    h[6] = (_Float16)v1.z; h[7] = (_Float16)v1.w;
    *(half8v*)&xh[base] = h;
  } else {
    int m = b - 3072;
    const float* W; _Float16* Wt; int K, C;
    if (m == 0)      { W = Wl1;  Wt = Wl1t;  K = 128; C = 128; }
    else if (m == 1) { W = Wr1;  Wt = Wr1t;  K = 128; C = 128; }
    else if (m == 2) { W = Wl2;  Wt = Wl2t;  K = 128; C = 64;  }
    else if (m == 3) { W = Wr2;  Wt = Wr2t;  K = 128; C = 64;  }
    else             { W = Wlin; Wt = Wlint; K = 64;  C = 128; }
    int sh = (C == 128) ? 7 : 6;
    for (int i = t; i < K * C; i += 256) {
      int k = i >> sh, c = i & (C - 1);
      Wt[c * K + k] = (_Float16)W[i];
    }
  }
}

__global__ __launch_bounds__(1024) void scan_kernel(const int* __restrict__ deg,
                                                    int* __restrict__ row_ptr,
                                                    int* __restrict__ cursor,
                                                    float* __restrict__ deg_inv) {
  __shared__ int part[1024];
  int t = threadIdx.x;
  int base = t * 16;
  int loc[16];
  int s = 0;
#pragma unroll
  for (int i = 0; i < 16; ++i) { loc[i] = deg[base + i]; s += loc[i]; }
  part[t] = s;
  __syncthreads();
  for (int off = 1; off < 1024; off <<= 1) {
    int v = (t >= off) ? part[t - off] : 0;
    __syncthreads();
    part[t] += v;
    __syncthreads();
  }
  int run = (t == 0) ? 0 : part[t - 1];
#pragma unroll
  for (int i = 0; i < 16; ++i) {
    row_ptr[base + i] = run;
    cursor[base + i] = run;
    int d = loc[i];
    deg_inv[base + i] = 1.0f / (float)(d > 0 ? d : 1);
    run += d;
  }
  if (t == 1023) row_ptr[N_NODES] = run;
}

__global__ __launch_bounds__(256) void scatter_kernel(const int* __restrict__ src,
                                                      const int* __restrict__ dst,
                                                      int* __restrict__ cursor,
                                                      int* __restrict__ col_idx) {
  int e = blockIdx.x * 256 + threadIdx.x;
  int d = dst[e];
  int pos = atomicAdd(&cursor[d], 1);
  col_idx[pos] = src[e];
}

// ---------------- mean aggregation: f16 rows (256 B), 4 edges per wave-load ----------

__global__ __launch_bounds__(512) void aggregate_f16_kernel(const _Float16* __restrict__ feat,
                                                            const int* __restrict__ row_ptr,
                                                            const int* __restrict__ col_idx,
                                                            const float* __restrict__ deg_inv,
                                                            _Float16* __restrict__ out) {
  int node = blockIdx.x * 8 + (threadIdx.x >> 6);
  int lane = threadIdx.x & 63;
  int g = lane >> 4, fl = lane & 15;
  int beg = row_ptr[node], end = row_ptr[node + 1];
  float acc[8] = {};
  for (int base = beg; base < end; base += 64) {
    int rem = end - base;
    int cnt = rem < 64 ? rem : 64;
    int idx = (lane < cnt) ? col_idx[base + lane] : 0;
    int jmain = cnt & ~15;
    for (int j = 0; j < jmain; j += 16) {
#pragma unroll
      for (int u = 0; u < 4; ++u) {
        int s = __shfl(idx, j + u * 4 + g);
        half8v v = *(const half8v*)&feat[(size_t)s * 128 + fl * 8];
#pragma unroll
        for (int i = 0; i < 8; ++i) acc[i] += (float)v[i];
      }
    }
    for (int j = jmain; j < cnt; j += 4) {
      int s = __shfl(idx, j + g);
      if (j + g < cnt) {
        half8v v = *(const half8v*)&feat[(size_t)s * 128 + fl * 8];
#pragma unroll
        for (int i = 0; i < 8; ++i) acc[i] += (float)v[i];
      }
    }
  }
#pragma unroll
  for (int i = 0; i < 8; ++i) {
    acc[i] += __shfl_xor(acc[i], 16);
    acc[i] += __shfl_xor(acc[i], 32);
  }
  if (g == 0) {
    float inv = deg_inv[node];
    half8v r;
#pragma unroll
    for (int i = 0; i < 8; ++i) r[i] = (_Float16)(acc[i] * inv);
    *(half8v*)&out[(size_t)node * 128 + fl * 8] = r;
  }
}

// ---------------- SAGE layer 1 (MFMA): hh = f16(aggr@Wl1 + x@Wr1 + b1) ----------------

__global__ __launch_bounds__(256) void sage1_mfma_kernel(const _Float16* __restrict__ aggr,
                                                         const _Float16* __restrict__ self,
                                                         const _Float16* __restrict__ Wlt,
                                                         const _Float16* __restrict__ Wrt,
                                                         const float* __restrict__ bias,
                                                         _Float16* __restrict__ hh) {
  int t = threadIdx.x;
  int lane = t & 63, w = t >> 6;
  int wr = w >> 1, wc = w & 1;
  int lmod = lane & 31, lhalf = lane >> 5;
  int row0 = blockIdx.x * 64 + wr * 32;
  int c0 = wc * 64;
  floatx16 acc[2] = {};
#pragma unroll
  for (int kc = 0; kc < 8; ++kc) {
    int ko = kc * 16 + lhalf * 8;
    half8v a = *(const half8v*)&aggr[(size_t)(row0 + lmod) * 128 + ko];
    half8v b0 = *(const half8v*)&Wlt[(size_t)(c0 + lmod) * 128 + ko];
    half8v b1 = *(const half8v*)&Wlt[(size_t)(c0 + 32 + lmod) * 128 + ko];
    acc[0] = MFMA16(a, b0, acc[0]);
    acc[1] = MFMA16(a, b1, acc[1]);
  }
#pragma unroll
  for (int kc = 0; kc < 8; ++kc) {
    int ko = kc * 16 + lhalf * 8;
    half8v a = *(const half8v*)&self[(size_t)(row0 + lmod) * 128 + ko];
    half8v b0 = *(const half8v*)&Wrt[(size_t)(c0 + lmod) * 128 + ko];
    half8v b1 = *(const half8v*)&Wrt[(size_t)(c0 + 32 + lmod) * 128 + ko];
    acc[0] = MFMA16(a, b0, acc[0]);
    acc[1] = MFMA16(a, b1, acc[1]);
  }
#pragma unroll
  for (int ct = 0; ct < 2; ++ct) {
    float bv = bias[c0 + ct * 32 + lmod];
#pragma unroll
    for (int reg = 0; reg < 16; ++reg) {
      int r = (reg & 3) + 8 * (reg >> 2) + 4 * lhalf;
      hh[(size_t)(row0 + r) * 128 + c0 + ct * 32 + lmod] = (_Float16)(acc[ct][reg] + bv);
    }
  }
}

// ---------------- fused SAGE layer 2 + normalize + lin_elu (MFMA) ----------------

__global__ __launch_bounds__(256) void sage2_fused_kernel(const _Float16* __restrict__ aggr,
                                                          const _Float16* __restrict__ self,
                                                          const _Float16* __restrict__ Wlt,
                                                          const _Float16* __restrict__ Wrt,
                                                          const float* __restrict__ bias,
                                                          const _Float16* __restrict__ Wlint,
                                                          const float* __restrict__ b_lin,
                                                          float* __restrict__ z,
                                                          _Float16* __restrict__ zh,
                                                          float* __restrict__ xo) {
  __shared__ float lds2[64][65];
  __shared__ float rinv[64];
  int t = threadIdx.x;
  int lane = t & 63, w = t >> 6;
  int wr = w >> 1, wc = w & 1;
  int lmod = lane & 31, lhalf = lane >> 5;
  int rowb = blockIdx.x * 64;
  int row0 = rowb + wr * 32;
  int c0 = wc * 32;

  floatx16 acc = {};
#pragma unroll
  for (int kc = 0; kc < 8; ++kc) {
    int ko = kc * 16 + lhalf * 8;
    half8v a = *(const half8v*)&aggr[(size_t)(row0 + lmod) * 128 + ko];
    half8v b = *(const half8v*)&Wlt[(size_t)(c0 + lmod) * 128 + ko];
    acc = MFMA16(a, b, acc);
  }
#pragma unroll
  for (int kc = 0; kc < 8; ++kc) {
    int ko = kc * 16 + lhalf * 8;
    half8v a = *(const half8v*)&self[(size_t)(row0 + lmod) * 128 + ko];
    half8v b = *(const half8v*)&Wrt[(size_t)(c0 + lmod) * 128 + ko];
    acc = MFMA16(a, b, acc);
  }
  float bv = bias[c0 + lmod];
#pragma unroll
  for (int reg = 0; reg < 16; ++reg) {
    int r = (reg & 3) + 8 * (reg >> 2) + 4 * lhalf;
    lds2[wr * 32 + r][c0 + lmod] = acc[reg] + bv;
  }
  __syncthreads();
  if (t < 64) {
    float s = 0.f;
#pragma unroll 16
    for (int i = 0; i < 64; ++i) { float v = lds2[t][i]; s += v * v; }
    rinv[t] = 1.0f / fmaxf(sqrtf(s), 1e-12f);
  }
  __syncthreads();
  {
    int row = t >> 2;
    int cb = (t & 3) * 16;
    float inv = rinv[row];
#pragma unroll
    for (int q = 0; q < 4; ++q) {
      int c = cb + q * 4;
      float o0 = lds2[row][c] * inv;
      float o1 = lds2[row][c + 1] * inv;
      float o2 = lds2[row][c + 2] * inv;
      float o3 = lds2[row][c + 3] * inv;
      lds2[row][c] = o0; lds2[row][c + 1] = o1;
      lds2[row][c + 2] = o2; lds2[row][c + 3] = o3;
      float4 zo; zo.x = o0; zo.y = o1; zo.z = o2; zo.w = o3;
      *(float4*)&z[(size_t)(rowb + row) * 64 + c] = zo;
      half4v hv;
      hv[0] = (_Float16)o0; hv[1] = (_Float16)o1;
      hv[2] = (_Float16)o2; hv[3] = (_Float16)o3;
      *(half4v*)&zh[(size_t)(rowb + row) * 64 + c] = hv;
    }
  }
  __syncthreads();
  floatx16 acc2[2] = {};
#pragma unroll
  for (int kc = 0; kc < 4; ++kc) {
    half8v a0, a1;
#pragma unroll
    for (int i = 0; i < 8; ++i) {
      int k = kc * 16 + lhalf * 8 + i;
      a0[i] = (_Float16)lds2[lmod][k];
      a1[i] = (_Float16)lds2[32 + lmod][k];
    }
    half8v b = *(const half8v*)&Wlint[(size_t)(w * 32 + lmod) * 64 + kc * 16 + lhalf * 8];
    acc2[0] = MFMA16(a0, b, acc2[0]);
    acc2[1] = MFMA16(a1, b, acc2[1]);
  }
  float blv = b_lin[w * 32 + lmod];
#pragma unroll
  for (int rg = 0; rg < 2; ++rg) {
#pragma unroll
    for (int reg = 0; reg < 16; ++reg) {
      int r = rg * 32 + (reg & 3) + 8 * (reg >> 2) + 4 * lhalf;
      float v = acc2[rg][reg] + blv;
      v = v > 0.f ? v : expm1f(v);
      xo[(size_t)(rowb + r) * 128 + w * 32 + lmod] = v;
    }
  }
}

// ---------------- A_pred = sigmoid(z z^T), v6: r6 structure + f16 staging + poly ------
// r6's 64x512 tile / band epilogue / nt 1KB runs, with two changes:
// (1) stage acc as f16 -> LDS 64->32 KB -> 4 blocks/CU (2x store-phase overlap);
// (2) sigma(x) for x in [-1,1] via odd poly 0.5 + x(0.25 + x^2(-1/48 + 0.0019 x^2)),
//     max err ~2e-5 -- replaces exp+rcp (quarter-rate) with full-rate FMAs.

__device__ __forceinline__ floatx4 sig4(half4v h) {
  floatx4 r;
#pragma unroll
  for (int i = 0; i < 4; ++i) {
    float x = (float)h[i];
    float x2 = x * x;
    r[i] = 0.5f + x * (0.25f + x2 * (-0.02083333f + x2 * 0.0019f));
  }
  return r;
}

__global__ __launch_bounds__(512, 4) void apred_kernel(const _Float16* __restrict__ zh,
                                                       float* __restrict__ out) {
  __shared__ _Float16 lds[32][512];   // 32 KB -> 4 blocks/CU
  int t = threadIdx.x;
  int lane = t & 63;
  int w = t >> 6;
  int lmod = lane & 31, lhalf = lane >> 5;
  int bid = blockIdx.x;
  int lid = (bid & 7) * 1024 + (bid >> 3);
  int rbase = (lid >> 5) * 64;
  int cbase = (lid & 31) * 512;
  int cw = cbase + w * 64;

  floatx16 acc[2][2] = {};
#pragma unroll
  for (int kc = 0; kc < 4; ++kc) {
    int ko = kc * 16 + lhalf * 8;
    half8v a0 = *(const half8v*)&zh[(size_t)(rbase + lmod) * 64 + ko];
    half8v a1 = *(const half8v*)&zh[(size_t)(rbase + 32 + lmod) * 64 + ko];
    half8v b0 = *(const half8v*)&zh[(size_t)(cw + lmod) * 64 + ko];
    half8v b1 = *(const half8v*)&zh[(size_t)(cw + 32 + lmod) * 64 + ko];
    acc[0][0] = MFMA16(a0, b0, acc[0][0]);
    acc[0][1] = MFMA16(a0, b1, acc[0][1]);
    acc[1][0] = MFMA16(a1, b0, acc[1][0]);
    acc[1][1] = MFMA16(a1, b1, acc[1][1]);
  }

#pragma unroll
  for (int band = 0; band < 2; ++band) {
    if (band) __syncthreads();
#pragma unroll
    for (int ct = 0; ct < 2; ++ct) {
#pragma unroll
      for (int reg = 0; reg < 16; ++reg) {
        int r = (reg & 3) + 8 * (reg >> 2) + 4 * lhalf;
        lds[r][w * 64 + ct * 32 + lmod] = (_Float16)acc[band][ct][reg];
      }
    }
    __syncthreads();
    // wave w stores rows {p*8 + w}: two contiguous 1 KB nt runs per row
#pragma unroll
    for (int p = 0; p < 4; ++p) {
      int row = p * 8 + w;
      half4v v0 = *(const half4v*)&lds[row][lane * 4];
      half4v v1 = *(const half4v*)&lds[row][256 + lane * 4];
      floatx4 sg0 = sig4(v0);
      floatx4 sg1 = sig4(v1);
      size_t addr = (size_t)(rbase + band * 32 + row) * N_NODES + cbase + lane * 4;
      __builtin_nontemporal_store(sg0, (floatx4*)&out[addr]);
      __builtin_nontemporal_store(sg1, (floatx4*)&out[addr + 256]);
    }
  }
}

// ---------------- launch ----------------

extern "C" void kernel_launch(void* const* d_in, const int* in_sizes, int n_in,
                              void* d_out, int out_size, void* d_ws, size_t ws_size,
                              hipStream_t stream) {
  const float* x = (const float*)d_in[0];
  const float* W_l1 = (const float*)d_in[1];
  const float* W_r1 = (const float*)d_in[2];
  const float* b1 = (const float*)d_in[3];
  const float* W_l2 = (const float*)d_in[4];
  const float* W_r2 = (const float*)d_in[5];
  const float* b2 = (const float*)d_in[6];
  const float* W_lin = (const float*)d_in[7];
  const float* b_lin = (const float*)d_in[8];
  const int* edge = (const int*)d_in[9];
  const int* esrc = edge;
  const int* edst = edge + N_EDGES;

  int* deg = (int*)d_ws;
  int* row_ptr = deg + 16384;
  int* cursor = row_ptr + 16448;
  float* deg_inv = (float*)(cursor + 16384);
  int* col_idx = (int*)(deg_inv + 16384);
  _Float16* xh = (_Float16*)(col_idx + N_EDGES);
  _Float16* hh = xh + (size_t)N_NODES * 128;
  _Float16* aggh = hh + (size_t)N_NODES * 128;
  _Float16* zh = aggh + (size_t)N_NODES * 128;
  _Float16* Wl1t = zh + (size_t)N_NODES * 64;
  _Float16* Wr1t = Wl1t + 16384;
  _Float16* Wl2t = Wr1t + 16384;
  _Float16* Wr2t = Wl2t + 8192;
  _Float16* Wlint = Wr2t + 8192;

  float* A = (float*)d_out;
  float* z = A + (size_t)N_NODES * N_NODES;
  float* xo = z + (size_t)N_NODES * 64;

  (void)hipMemsetAsync(deg, 0, N_NODES * sizeof(int), stream);
  hist_prep_kernel<<<3077, 256, 0, stream>>>(edst, deg, x, xh,
                                             W_l1, W_r1, W_l2, W_r2, W_lin,
                                             Wl1t, Wr1t, Wl2t, Wr2t, Wlint);
  scan_kernel<<<1, 1024, 0, stream>>>(deg, row_ptr, cursor, deg_inv);
  scatter_kernel<<<N_EDGES / 256, 256, 0, stream>>>(esrc, edst, cursor, col_idx);

  aggregate_f16_kernel<<<N_NODES / 8, 512, 0, stream>>>(xh, row_ptr, col_idx, deg_inv, aggh);
  sage1_mfma_kernel<<<N_NODES / 64, 256, 0, stream>>>(aggh, xh, Wl1t, Wr1t, b1, hh);
  aggregate_f16_kernel<<<N_NODES / 8, 512, 0, stream>>>(hh, row_ptr, col_idx, deg_inv, aggh);
  sage2_fused_kernel<<<N_NODES / 64, 256, 0, stream>>>(aggh, hh, Wl2t, Wr2t, b2,
                                                       Wlint, b_lin, z, zh, xo);

  apred_kernel<<<8192, 512, 0, stream>>>(zh, A);
}

// Round 12
// 307.598 us; speedup vs baseline: 1.0229x; 1.0229x over previous
//
#include <hip/hip_runtime.h>

#define N_NODES 16384
#define N_EDGES 524288

typedef _Float16 half8v __attribute__((ext_vector_type(8)));
typedef _Float16 half4v __attribute__((ext_vector_type(4)));
typedef float floatx16 __attribute__((ext_vector_type(16)));
typedef float floatx4 __attribute__((ext_vector_type(4)));

#define MFMA16(a, b, c) __builtin_amdgcn_mfma_f32_32x32x16_f16(a, b, c, 0, 0, 0)

// ---------------- fused CSR-hist + f16 prep ----------------

__global__ __launch_bounds__(256) void hist_prep_kernel(const int* __restrict__ dst,
                                                        int* __restrict__ deg,
                                                        const float* __restrict__ x,
                                                        _Float16* __restrict__ xh,
                                                        const float* __restrict__ Wl1,
                                                        const float* __restrict__ Wr1,
                                                        const float* __restrict__ Wl2,
                                                        const float* __restrict__ Wr2,
                                                        const float* __restrict__ Wlin,
                                                        _Float16* __restrict__ Wl1t,
                                                        _Float16* __restrict__ Wr1t,
                                                        _Float16* __restrict__ Wl2t,
                                                        _Float16* __restrict__ Wr2t,
                                                        _Float16* __restrict__ Wlint) {
  int b = blockIdx.x, t = threadIdx.x;
  if (b < 2048) {
    int e = b * 256 + t;
    atomicAdd(&deg[dst[e]], 1);
  } else if (b < 3072) {
    int bb = b - 2048;
    size_t base = (size_t)bb * 2048 + t * 8;
    float4 v0 = *(const float4*)&x[base];
    float4 v1 = *(const float4*)&x[base + 4];
    half8v h;
    h[0] = (_Float16)v0.x; h[1] = (_Float16)v0.y;
    h[2] = (_Float16)v0.z; h[3] = (_Float16)v0.w;
    h[4] = (_Float16)v1.x; h[5] = (_Float16)v1.y;
    h[6] = (_Float16)v1.z; h[7] = (_Float16)v1.w;
    *(half8v*)&xh[base] = h;
  } else {
    int m = b - 3072;
    const float* W; _Float16* Wt; int K, C;
    if (m == 0)      { W = Wl1;  Wt = Wl1t;  K = 128; C = 128; }
    else if (m == 1) { W = Wr1;  Wt = Wr1t;  K = 128; C = 128; }
    else if (m == 2) { W = Wl2;  Wt = Wl2t;  K = 128; C = 64;  }
    else if (m == 3) { W = Wr2;  Wt = Wr2t;  K = 128; C = 64;  }
    else             { W = Wlin; Wt = Wlint; K = 64;  C = 128; }
    int sh = (C == 128) ? 7 : 6;
    for (int i = t; i < K * C; i += 256) {
      int k = i >> sh, c = i & (C - 1);
      Wt[c * K + k] = (_Float16)W[i];
    }
  }
}

__global__ __launch_bounds__(1024) void scan_kernel(const int* __restrict__ deg,
                                                    int* __restrict__ row_ptr,
                                                    int* __restrict__ cursor,
                                                    float* __restrict__ deg_inv) {
  __shared__ int part[1024];
  int t = threadIdx.x;
  int base = t * 16;
  int loc[16];
  int s = 0;
#pragma unroll
  for (int i = 0; i < 16; ++i) { loc[i] = deg[base + i]; s += loc[i]; }
  part[t] = s;
  __syncthreads();
  for (int off = 1; off < 1024; off <<= 1) {
    int v = (t >= off) ? part[t - off] : 0;
    __syncthreads();
    part[t] += v;
    __syncthreads();
  }
  int run = (t == 0) ? 0 : part[t - 1];
#pragma unroll
  for (int i = 0; i < 16; ++i) {
    row_ptr[base + i] = run;
    cursor[base + i] = run;
    int d = loc[i];
    deg_inv[base + i] = 1.0f / (float)(d > 0 ? d : 1);
    run += d;
  }
  if (t == 1023) row_ptr[N_NODES] = run;
}

__global__ __launch_bounds__(256) void scatter_kernel(const int* __restrict__ src,
                                                      const int* __restrict__ dst,
                                                      int* __restrict__ cursor,
                                                      int* __restrict__ col_idx) {
  int e = blockIdx.x * 256 + threadIdx.x;
  int d = dst[e];
  int pos = atomicAdd(&cursor[d], 1);
  col_idx[pos] = src[e];
}

// ---------------- mean aggregation: f16 rows (256 B), 4 edges per wave-load ----------

__global__ __launch_bounds__(512) void aggregate_f16_kernel(const _Float16* __restrict__ feat,
                                                            const int* __restrict__ row_ptr,
                                                            const int* __restrict__ col_idx,
                                                            const float* __restrict__ deg_inv,
                                                            _Float16* __restrict__ out) {
  int node = blockIdx.x * 8 + (threadIdx.x >> 6);
  int lane = threadIdx.x & 63;
  int g = lane >> 4, fl = lane & 15;
  int beg = row_ptr[node], end = row_ptr[node + 1];
  float acc[8] = {};
  for (int base = beg; base < end; base += 64) {
    int rem = end - base;
    int cnt = rem < 64 ? rem : 64;
    int idx = (lane < cnt) ? col_idx[base + lane] : 0;
    int jmain = cnt & ~15;
    for (int j = 0; j < jmain; j += 16) {
#pragma unroll
      for (int u = 0; u < 4; ++u) {
        int s = __shfl(idx, j + u * 4 + g);
        half8v v = *(const half8v*)&feat[(size_t)s * 128 + fl * 8];
#pragma unroll
        for (int i = 0; i < 8; ++i) acc[i] += (float)v[i];
      }
    }
    for (int j = jmain; j < cnt; j += 4) {
      int s = __shfl(idx, j + g);
      if (j + g < cnt) {
        half8v v = *(const half8v*)&feat[(size_t)s * 128 + fl * 8];
#pragma unroll
        for (int i = 0; i < 8; ++i) acc[i] += (float)v[i];
      }
    }
  }
#pragma unroll
  for (int i = 0; i < 8; ++i) {
    acc[i] += __shfl_xor(acc[i], 16);
    acc[i] += __shfl_xor(acc[i], 32);
  }
  if (g == 0) {
    float inv = deg_inv[node];
    half8v r;
#pragma unroll
    for (int i = 0; i < 8; ++i) r[i] = (_Float16)(acc[i] * inv);
    *(half8v*)&out[(size_t)node * 128 + fl * 8] = r;
  }
}

// ---------------- SAGE layer 1 (MFMA): hh = f16(aggr@Wl1 + x@Wr1 + b1) ----------------

__global__ __launch_bounds__(256) void sage1_mfma_kernel(const _Float16* __restrict__ aggr,
                                                         const _Float16* __restrict__ self,
                                                         const _Float16* __restrict__ Wlt,
                                                         const _Float16* __restrict__ Wrt,
                                                         const float* __restrict__ bias,
                                                         _Float16* __restrict__ hh) {
  int t = threadIdx.x;
  int lane = t & 63, w = t >> 6;
  int wr = w >> 1, wc = w & 1;
  int lmod = lane & 31, lhalf = lane >> 5;
  int row0 = blockIdx.x * 64 + wr * 32;
  int c0 = wc * 64;
  floatx16 acc[2] = {};
#pragma unroll
  for (int kc = 0; kc < 8; ++kc) {
    int ko = kc * 16 + lhalf * 8;
    half8v a = *(const half8v*)&aggr[(size_t)(row0 + lmod) * 128 + ko];
    half8v b0 = *(const half8v*)&Wlt[(size_t)(c0 + lmod) * 128 + ko];
    half8v b1 = *(const half8v*)&Wlt[(size_t)(c0 + 32 + lmod) * 128 + ko];
    acc[0] = MFMA16(a, b0, acc[0]);
    acc[1] = MFMA16(a, b1, acc[1]);
  }
#pragma unroll
  for (int kc = 0; kc < 8; ++kc) {
    int ko = kc * 16 + lhalf * 8;
    half8v a = *(const half8v*)&self[(size_t)(row0 + lmod) * 128 + ko];
    half8v b0 = *(const half8v*)&Wrt[(size_t)(c0 + lmod) * 128 + ko];
    half8v b1 = *(const half8v*)&Wrt[(size_t)(c0 + 32 + lmod) * 128 + ko];
    acc[0] = MFMA16(a, b0, acc[0]);
    acc[1] = MFMA16(a, b1, acc[1]);
  }
#pragma unroll
  for (int ct = 0; ct < 2; ++ct) {
    float bv = bias[c0 + ct * 32 + lmod];
#pragma unroll
    for (int reg = 0; reg < 16; ++reg) {
      int r = (reg & 3) + 8 * (reg >> 2) + 4 * lhalf;
      hh[(size_t)(row0 + r) * 128 + c0 + ct * 32 + lmod] = (_Float16)(acc[ct][reg] + bv);
    }
  }
}

// ---------------- fused SAGE layer 2 + normalize + lin_elu (MFMA) ----------------

__global__ __launch_bounds__(256) void sage2_fused_kernel(const _Float16* __restrict__ aggr,
                                                          const _Float16* __restrict__ self,
                                                          const _Float16* __restrict__ Wlt,
                                                          const _Float16* __restrict__ Wrt,
                                                          const float* __restrict__ bias,
                                                          const _Float16* __restrict__ Wlint,
                                                          const float* __restrict__ b_lin,
                                                          float* __restrict__ z,
                                                          _Float16* __restrict__ zh,
                                                          float* __restrict__ xo) {
  __shared__ float lds2[64][65];
  __shared__ float rinv[64];
  int t = threadIdx.x;
  int lane = t & 63, w = t >> 6;
  int wr = w >> 1, wc = w & 1;
  int lmod = lane & 31, lhalf = lane >> 5;
  int rowb = blockIdx.x * 64;
  int row0 = rowb + wr * 32;
  int c0 = wc * 32;

  floatx16 acc = {};
#pragma unroll
  for (int kc = 0; kc < 8; ++kc) {
    int ko = kc * 16 + lhalf * 8;
    half8v a = *(const half8v*)&aggr[(size_t)(row0 + lmod) * 128 + ko];
    half8v b = *(const half8v*)&Wlt[(size_t)(c0 + lmod) * 128 + ko];
    acc = MFMA16(a, b, acc);
  }
#pragma unroll
  for (int kc = 0; kc < 8; ++kc) {
    int ko = kc * 16 + lhalf * 8;
    half8v a = *(const half8v*)&self[(size_t)(row0 + lmod) * 128 + ko];
    half8v b = *(const half8v*)&Wrt[(size_t)(c0 + lmod) * 128 + ko];
    acc = MFMA16(a, b, acc);
  }
  float bv = bias[c0 + lmod];
#pragma unroll
  for (int reg = 0; reg < 16; ++reg) {
    int r = (reg & 3) + 8 * (reg >> 2) + 4 * lhalf;
    lds2[wr * 32 + r][c0 + lmod] = acc[reg] + bv;
  }
  __syncthreads();
  if (t < 64) {
    float s = 0.f;
#pragma unroll 16
    for (int i = 0; i < 64; ++i) { float v = lds2[t][i]; s += v * v; }
    rinv[t] = 1.0f / fmaxf(sqrtf(s), 1e-12f);
  }
  __syncthreads();
  {
    int row = t >> 2;
    int cb = (t & 3) * 16;
    float inv = rinv[row];
#pragma unroll
    for (int q = 0; q < 4; ++q) {
      int c = cb + q * 4;
      float o0 = lds2[row][c] * inv;
      float o1 = lds2[row][c + 1] * inv;
      float o2 = lds2[row][c + 2] * inv;
      float o3 = lds2[row][c + 3] * inv;
      lds2[row][c] = o0; lds2[row][c + 1] = o1;
      lds2[row][c + 2] = o2; lds2[row][c + 3] = o3;
      float4 zo; zo.x = o0; zo.y = o1; zo.z = o2; zo.w = o3;
      *(float4*)&z[(size_t)(rowb + row) * 64 + c] = zo;
      half4v hv;
      hv[0] = (_Float16)o0; hv[1] = (_Float16)o1;
      hv[2] = (_Float16)o2; hv[3] = (_Float16)o3;
      *(half4v*)&zh[(size_t)(rowb + row) * 64 + c] = hv;
    }
  }
  __syncthreads();
  floatx16 acc2[2] = {};
#pragma unroll
  for (int kc = 0; kc < 4; ++kc) {
    half8v a0, a1;
#pragma unroll
    for (int i = 0; i < 8; ++i) {
      int k = kc * 16 + lhalf * 8 + i;
      a0[i] = (_Float16)lds2[lmod][k];
      a1[i] = (_Float16)lds2[32 + lmod][k];
    }
    half8v b = *(const half8v*)&Wlint[(size_t)(w * 32 + lmod) * 64 + kc * 16 + lhalf * 8];
    acc2[0] = MFMA16(a0, b, acc2[0]);
    acc2[1] = MFMA16(a1, b, acc2[1]);
  }
  float blv = b_lin[w * 32 + lmod];
#pragma unroll
  for (int rg = 0; rg < 2; ++rg) {
#pragma unroll
    for (int reg = 0; reg < 16; ++reg) {
      int r = rg * 32 + (reg & 3) + 8 * (reg >> 2) + 4 * lhalf;
      float v = acc2[rg][reg] + blv;
      v = v > 0.f ? v : expm1f(v);
      xo[(size_t)(rowb + r) * 128 + w * 32 + lmod] = v;
    }
  }
}

// ---------------- A_pred = sigmoid(z z^T): r6 structure + poly sigmoid ONLY ----------
// Single-variable A/B vs the 298-us r6 baseline: f32 staging, 64 KB LDS,
// 2 blocks/CU, nt 1KB-run stores, XCD swizzle -- all identical. Only change:
// sigma(x), x = z.z in [-1,1], via odd poly 0.5 + x(0.25 + x^2(-1/48 + 0.0019x^2))
// (max err ~2e-5) -- removes 2 quarter-rate transcendentals per element from the
// post-barrier store phase.

__device__ __forceinline__ floatx4 sig4(floatx4 v) {
  floatx4 r;
#pragma unroll
  for (int i = 0; i < 4; ++i) {
    float x = v[i];
    float x2 = x * x;
    r[i] = 0.5f + x * (0.25f + x2 * (-0.02083333f + x2 * 0.0019f));
  }
  return r;
}

__global__ __launch_bounds__(512, 4) void apred_kernel(const _Float16* __restrict__ zh,
                                                       float* __restrict__ out) {
  __shared__ float lds[32][512];
  int t = threadIdx.x;
  int lane = t & 63;
  int w = t >> 6;
  int lmod = lane & 31, lhalf = lane >> 5;
  int bid = blockIdx.x;
  int lid = (bid & 7) * 1024 + (bid >> 3);
  int rbase = (lid >> 5) * 64;
  int cbase = (lid & 31) * 512;
  int cw = cbase + w * 64;

  floatx16 acc[2][2] = {};
#pragma unroll
  for (int kc = 0; kc < 4; ++kc) {
    int ko = kc * 16 + lhalf * 8;
    half8v a0 = *(const half8v*)&zh[(size_t)(rbase + lmod) * 64 + ko];
    half8v a1 = *(const half8v*)&zh[(size_t)(rbase + 32 + lmod) * 64 + ko];
    half8v b0 = *(const half8v*)&zh[(size_t)(cw + lmod) * 64 + ko];
    half8v b1 = *(const half8v*)&zh[(size_t)(cw + 32 + lmod) * 64 + ko];
    acc[0][0] = MFMA16(a0, b0, acc[0][0]);
    acc[0][1] = MFMA16(a0, b1, acc[0][1]);
    acc[1][0] = MFMA16(a1, b0, acc[1][0]);
    acc[1][1] = MFMA16(a1, b1, acc[1][1]);
  }

#pragma unroll
  for (int band = 0; band < 2; ++band) {
    if (band) __syncthreads();
#pragma unroll
    for (int ct = 0; ct < 2; ++ct) {
#pragma unroll
      for (int reg = 0; reg < 16; ++reg) {
        int r = (reg & 3) + 8 * (reg >> 2) + 4 * lhalf;
        lds[r][w * 64 + ct * 32 + lmod] = acc[band][ct][reg];
      }
    }
    __syncthreads();
#pragma unroll
    for (int j = 0; j < 4; ++j) {
      int row = j * 8 + w;
      int col = lane * 4;
      floatx4 v0 = *(const floatx4*)&lds[row][col];
      floatx4 sg0 = sig4(v0);
      size_t addr = (size_t)(rbase + band * 32 + row) * N_NODES + cbase + col;
      __builtin_nontemporal_store(sg0, (floatx4*)&out[addr]);
      floatx4 v1 = *(const floatx4*)&lds[row][256 + col];
      floatx4 sg1 = sig4(v1);
      __builtin_nontemporal_store(sg1, (floatx4*)&out[addr + 256]);
    }
  }
}

// ---------------- launch ----------------

extern "C" void kernel_launch(void* const* d_in, const int* in_sizes, int n_in,
                              void* d_out, int out_size, void* d_ws, size_t ws_size,
                              hipStream_t stream) {
  const float* x = (const float*)d_in[0];
  const float* W_l1 = (const float*)d_in[1];
  const float* W_r1 = (const float*)d_in[2];
  const float* b1 = (const float*)d_in[3];
  const float* W_l2 = (const float*)d_in[4];
  const float* W_r2 = (const float*)d_in[5];
  const float* b2 = (const float*)d_in[6];
  const float* W_lin = (const float*)d_in[7];
  const float* b_lin = (const float*)d_in[8];
  const int* edge = (const int*)d_in[9];
  const int* esrc = edge;
  const int* edst = edge + N_EDGES;

  int* deg = (int*)d_ws;
  int* row_ptr = deg + 16384;
  int* cursor = row_ptr + 16448;
  float* deg_inv = (float*)(cursor + 16384);
  int* col_idx = (int*)(deg_inv + 16384);
  _Float16* xh = (_Float16*)(col_idx + N_EDGES);
  _Float16* hh = xh + (size_t)N_NODES * 128;
  _Float16* aggh = hh + (size_t)N_NODES * 128;
  _Float16* zh = aggh + (size_t)N_NODES * 128;
  _Float16* Wl1t = zh + (size_t)N_NODES * 64;
  _Float16* Wr1t = Wl1t + 16384;
  _Float16* Wl2t = Wr1t + 16384;
  _Float16* Wr2t = Wl2t + 8192;
  _Float16* Wlint = Wr2t + 8192;

  float* A = (float*)d_out;
  float* z = A + (size_t)N_NODES * N_NODES;
  float* xo = z + (size_t)N_NODES * 64;

  (void)hipMemsetAsync(deg, 0, N_NODES * sizeof(int), stream);
  hist_prep_kernel<<<3077, 256, 0, stream>>>(edst, deg, x, xh,
                                             W_l1, W_r1, W_l2, W_r2, W_lin,
                                             Wl1t, Wr1t, Wl2t, Wr2t, Wlint);
  scan_kernel<<<1, 1024, 0, stream>>>(deg, row_ptr, cursor, deg_inv);
  scatter_kernel<<<N_EDGES / 256, 256, 0, stream>>>(esrc, edst, cursor, col_idx);

  aggregate_f16_kernel<<<N_NODES / 8, 512, 0, stream>>>(xh, row_ptr, col_idx, deg_inv, aggh);
  sage1_mfma_kernel<<<N_NODES / 64, 256, 0, stream>>>(aggh, xh, Wl1t, Wr1t, b1, hh);
  aggregate_f16_kernel<<<N_NODES / 8, 512, 0, stream>>>(hh, row_ptr, col_idx, deg_inv, aggh);
  sage2_fused_kernel<<<N_NODES / 64, 256, 0, stream>>>(aggh, hh, Wl2t, Wr2t, b2,
                                                       Wlint, b_lin, z, zh, xo);

  apred_kernel<<<8192, 512, 0, stream>>>(zh, A);
}

// Round 13
// 301.288 us; speedup vs baseline: 1.0443x; 1.0209x over previous
//
#include <hip/hip_runtime.h>

#define N_NODES 16384
#define N_EDGES 524288

typedef _Float16 half8v __attribute__((ext_vector_type(8)));
typedef _Float16 half4v __attribute__((ext_vector_type(4)));
typedef float floatx16 __attribute__((ext_vector_type(16)));
typedef float floatx4 __attribute__((ext_vector_type(4)));

#define MFMA16(a, b, c) __builtin_amdgcn_mfma_f32_32x32x16_f16(a, b, c, 0, 0, 0)

// ---------------- fused CSR-hist + f16 prep ----------------

__global__ __launch_bounds__(256) void hist_prep_kernel(const int* __restrict__ dst,
                                                        int* __restrict__ deg,
                                                        const float* __restrict__ x,
                                                        _Float16* __restrict__ xh,
                                                        const float* __restrict__ Wl1,
                                                        const float* __restrict__ Wr1,
                                                        const float* __restrict__ Wl2,
                                                        const float* __restrict__ Wr2,
                                                        const float* __restrict__ Wlin,
                                                        _Float16* __restrict__ Wl1t,
                                                        _Float16* __restrict__ Wr1t,
                                                        _Float16* __restrict__ Wl2t,
                                                        _Float16* __restrict__ Wr2t,
                                                        _Float16* __restrict__ Wlint) {
  int b = blockIdx.x, t = threadIdx.x;
  if (b < 2048) {
    int e = b * 256 + t;
    atomicAdd(&deg[dst[e]], 1);
  } else if (b < 3072) {
    int bb = b - 2048;
    size_t base = (size_t)bb * 2048 + t * 8;
    float4 v0 = *(const float4*)&x[base];
    float4 v1 = *(const float4*)&x[base + 4];
    half8v h;
    h[0] = (_Float16)v0.x; h[1] = (_Float16)v0.y;
    h[2] = (_Float16)v0.z; h[3] = (_Float16)v0.w;
    h[4] = (_Float16)v1.x; h[5] = (_Float16)v1.y;
    h[6] = (_Float16)v1.z; h[7] = (_Float16)v1.w;
    *(half8v*)&xh[base] = h;
  } else {
    int m = b - 3072;
    const float* W; _Float16* Wt; int K, C;
    if (m == 0)      { W = Wl1;  Wt = Wl1t;  K = 128; C = 128; }
    else if (m == 1) { W = Wr1;  Wt = Wr1t;  K = 128; C = 128; }
    else if (m == 2) { W = Wl2;  Wt = Wl2t;  K = 128; C = 64;  }
    else if (m == 3) { W = Wr2;  Wt = Wr2t;  K = 128; C = 64;  }
    else             { W = Wlin; Wt = Wlint; K = 64;  C = 128; }
    int sh = (C == 128) ? 7 : 6;
    for (int i = t; i < K * C; i += 256) {
      int k = i >> sh, c = i & (C - 1);
      Wt[c * K + k] = (_Float16)W[i];
    }
  }
}

__global__ __launch_bounds__(1024) void scan_kernel(const int* __restrict__ deg,
                                                    int* __restrict__ row_ptr,
                                                    int* __restrict__ cursor,
                                                    float* __restrict__ deg_inv) {
  __shared__ int part[1024];
  int t = threadIdx.x;
  int base = t * 16;
  int loc[16];
  int s = 0;
#pragma unroll
  for (int i = 0; i < 16; ++i) { loc[i] = deg[base + i]; s += loc[i]; }
  part[t] = s;
  __syncthreads();
  for (int off = 1; off < 1024; off <<= 1) {
    int v = (t >= off) ? part[t - off] : 0;
    __syncthreads();
    part[t] += v;
    __syncthreads();
  }
  int run = (t == 0) ? 0 : part[t - 1];
#pragma unroll
  for (int i = 0; i < 16; ++i) {
    row_ptr[base + i] = run;
    cursor[base + i] = run;
    int d = loc[i];
    deg_inv[base + i] = 1.0f / (float)(d > 0 ? d : 1);
    run += d;
  }
  if (t == 1023) row_ptr[N_NODES] = run;
}

__global__ __launch_bounds__(256) void scatter_kernel(const int* __restrict__ src,
                                                      const int* __restrict__ dst,
                                                      int* __restrict__ cursor,
                                                      int* __restrict__ col_idx) {
  int e = blockIdx.x * 256 + threadIdx.x;
  int d = dst[e];
  int pos = atomicAdd(&cursor[d], 1);
  col_idx[pos] = src[e];
}

// ---------------- mean aggregation: f16 rows (256 B), 4 edges per wave-load ----------

__global__ __launch_bounds__(512) void aggregate_f16_kernel(const _Float16* __restrict__ feat,
                                                            const int* __restrict__ row_ptr,
                                                            const int* __restrict__ col_idx,
                                                            const float* __restrict__ deg_inv,
                                                            _Float16* __restrict__ out) {
  int node = blockIdx.x * 8 + (threadIdx.x >> 6);
  int lane = threadIdx.x & 63;
  int g = lane >> 4, fl = lane & 15;
  int beg = row_ptr[node], end = row_ptr[node + 1];
  float acc[8] = {};
  for (int base = beg; base < end; base += 64) {
    int rem = end - base;
    int cnt = rem < 64 ? rem : 64;
    int idx = (lane < cnt) ? col_idx[base + lane] : 0;
    int jmain = cnt & ~15;
    for (int j = 0; j < jmain; j += 16) {
#pragma unroll
      for (int u = 0; u < 4; ++u) {
        int s = __shfl(idx, j + u * 4 + g);
        half8v v = *(const half8v*)&feat[(size_t)s * 128 + fl * 8];
#pragma unroll
        for (int i = 0; i < 8; ++i) acc[i] += (float)v[i];
      }
    }
    for (int j = jmain; j < cnt; j += 4) {
      int s = __shfl(idx, j + g);
      if (j + g < cnt) {
        half8v v = *(const half8v*)&feat[(size_t)s * 128 + fl * 8];
#pragma unroll
        for (int i = 0; i < 8; ++i) acc[i] += (float)v[i];
      }
    }
  }
#pragma unroll
  for (int i = 0; i < 8; ++i) {
    acc[i] += __shfl_xor(acc[i], 16);
    acc[i] += __shfl_xor(acc[i], 32);
  }
  if (g == 0) {
    float inv = deg_inv[node];
    half8v r;
#pragma unroll
    for (int i = 0; i < 8; ++i) r[i] = (_Float16)(acc[i] * inv);
    *(half8v*)&out[(size_t)node * 128 + fl * 8] = r;
  }
}

// ---------------- SAGE layer 1 (MFMA): hh = f16(aggr@Wl1 + x@Wr1 + b1) ----------------

__global__ __launch_bounds__(256) void sage1_mfma_kernel(const _Float16* __restrict__ aggr,
                                                         const _Float16* __restrict__ self,
                                                         const _Float16* __restrict__ Wlt,
                                                         const _Float16* __restrict__ Wrt,
                                                         const float* __restrict__ bias,
                                                         _Float16* __restrict__ hh) {
  int t = threadIdx.x;
  int lane = t & 63, w = t >> 6;
  int wr = w >> 1, wc = w & 1;
  int lmod = lane & 31, lhalf = lane >> 5;
  int row0 = blockIdx.x * 64 + wr * 32;
  int c0 = wc * 64;
  floatx16 acc[2] = {};
#pragma unroll
  for (int kc = 0; kc < 8; ++kc) {
    int ko = kc * 16 + lhalf * 8;
    half8v a = *(const half8v*)&aggr[(size_t)(row0 + lmod) * 128 + ko];
    half8v b0 = *(const half8v*)&Wlt[(size_t)(c0 + lmod) * 128 + ko];
    half8v b1 = *(const half8v*)&Wlt[(size_t)(c0 + 32 + lmod) * 128 + ko];
    acc[0] = MFMA16(a, b0, acc[0]);
    acc[1] = MFMA16(a, b1, acc[1]);
  }
#pragma unroll
  for (int kc = 0; kc < 8; ++kc) {
    int ko = kc * 16 + lhalf * 8;
    half8v a = *(const half8v*)&self[(size_t)(row0 + lmod) * 128 + ko];
    half8v b0 = *(const half8v*)&Wrt[(size_t)(c0 + lmod) * 128 + ko];
    half8v b1 = *(const half8v*)&Wrt[(size_t)(c0 + 32 + lmod) * 128 + ko];
    acc[0] = MFMA16(a, b0, acc[0]);
    acc[1] = MFMA16(a, b1, acc[1]);
  }
#pragma unroll
  for (int ct = 0; ct < 2; ++ct) {
    float bv = bias[c0 + ct * 32 + lmod];
#pragma unroll
    for (int reg = 0; reg < 16; ++reg) {
      int r = (reg & 3) + 8 * (reg >> 2) + 4 * lhalf;
      hh[(size_t)(row0 + r) * 128 + c0 + ct * 32 + lmod] = (_Float16)(acc[ct][reg] + bv);
    }
  }
}

// ---------------- fused SAGE layer 2 + normalize + lin_elu (MFMA) ----------------

__global__ __launch_bounds__(256) void sage2_fused_kernel(const _Float16* __restrict__ aggr,
                                                          const _Float16* __restrict__ self,
                                                          const _Float16* __restrict__ Wlt,
                                                          const _Float16* __restrict__ Wrt,
                                                          const float* __restrict__ bias,
                                                          const _Float16* __restrict__ Wlint,
                                                          const float* __restrict__ b_lin,
                                                          float* __restrict__ z,
                                                          _Float16* __restrict__ zh,
                                                          float* __restrict__ xo) {
  __shared__ float lds2[64][65];
  __shared__ float rinv[64];
  int t = threadIdx.x;
  int lane = t & 63, w = t >> 6;
  int wr = w >> 1, wc = w & 1;
  int lmod = lane & 31, lhalf = lane >> 5;
  int rowb = blockIdx.x * 64;
  int row0 = rowb + wr * 32;
  int c0 = wc * 32;

  floatx16 acc = {};
#pragma unroll
  for (int kc = 0; kc < 8; ++kc) {
    int ko = kc * 16 + lhalf * 8;
    half8v a = *(const half8v*)&aggr[(size_t)(row0 + lmod) * 128 + ko];
    half8v b = *(const half8v*)&Wlt[(size_t)(c0 + lmod) * 128 + ko];
    acc = MFMA16(a, b, acc);
  }
#pragma unroll
  for (int kc = 0; kc < 8; ++kc) {
    int ko = kc * 16 + lhalf * 8;
    half8v a = *(const half8v*)&self[(size_t)(row0 + lmod) * 128 + ko];
    half8v b = *(const half8v*)&Wrt[(size_t)(c0 + lmod) * 128 + ko];
    acc = MFMA16(a, b, acc);
  }
  float bv = bias[c0 + lmod];
#pragma unroll
  for (int reg = 0; reg < 16; ++reg) {
    int r = (reg & 3) + 8 * (reg >> 2) + 4 * lhalf;
    lds2[wr * 32 + r][c0 + lmod] = acc[reg] + bv;
  }
  __syncthreads();
  if (t < 64) {
    float s = 0.f;
#pragma unroll 16
    for (int i = 0; i < 64; ++i) { float v = lds2[t][i]; s += v * v; }
    rinv[t] = 1.0f / fmaxf(sqrtf(s), 1e-12f);
  }
  __syncthreads();
  {
    int row = t >> 2;
    int cb = (t & 3) * 16;
    float inv = rinv[row];
#pragma unroll
    for (int q = 0; q < 4; ++q) {
      int c = cb + q * 4;
      float o0 = lds2[row][c] * inv;
      float o1 = lds2[row][c + 1] * inv;
      float o2 = lds2[row][c + 2] * inv;
      float o3 = lds2[row][c + 3] * inv;
      lds2[row][c] = o0; lds2[row][c + 1] = o1;
      lds2[row][c + 2] = o2; lds2[row][c + 3] = o3;
      float4 zo; zo.x = o0; zo.y = o1; zo.z = o2; zo.w = o3;
      *(float4*)&z[(size_t)(rowb + row) * 64 + c] = zo;
      half4v hv;
      hv[0] = (_Float16)o0; hv[1] = (_Float16)o1;
      hv[2] = (_Float16)o2; hv[3] = (_Float16)o3;
      *(half4v*)&zh[(size_t)(rowb + row) * 64 + c] = hv;
    }
  }
  __syncthreads();
  floatx16 acc2[2] = {};
#pragma unroll
  for (int kc = 0; kc < 4; ++kc) {
    half8v a0, a1;
#pragma unroll
    for (int i = 0; i < 8; ++i) {
      int k = kc * 16 + lhalf * 8 + i;
      a0[i] = (_Float16)lds2[lmod][k];
      a1[i] = (_Float16)lds2[32 + lmod][k];
    }
    half8v b = *(const half8v*)&Wlint[(size_t)(w * 32 + lmod) * 64 + kc * 16 + lhalf * 8];
    acc2[0] = MFMA16(a0, b, acc2[0]);
    acc2[1] = MFMA16(a1, b, acc2[1]);
  }
  float blv = b_lin[w * 32 + lmod];
#pragma unroll
  for (int rg = 0; rg < 2; ++rg) {
#pragma unroll
    for (int reg = 0; reg < 16; ++reg) {
      int r = rg * 32 + (reg & 3) + 8 * (reg >> 2) + 4 * lhalf;
      float v = acc2[rg][reg] + blv;
      v = v > 0.f ? v : expm1f(v);
      xo[(size_t)(rowb + r) * 128 + w * 32 + lmod] = v;
    }
  }
}

// ---------------- A_pred = sigmoid(z z^T): r6-exact final (measured best, 298 us) ----
// 64x512 tile, 8 waves (each 64x64 via 2x2 MFMA), f32 LDS staging (64 KB,
// 2 blocks/CU), band epilogue with 3 barriers, two contiguous 1 KB nt runs per
// store row, XCD-chunked swizzle. Seven controlled variants all measured worse:
// plain stores +49, per-strip drains +46, 1-barrier tiny blocks +104,
// f16-staging/4blk +16, poly-sigmoid null, linearity null, panel sweep +46.

__global__ __launch_bounds__(512, 4) void apred_kernel(const _Float16* __restrict__ zh,
                                                       float* __restrict__ out) {
  __shared__ float lds[32][512];
  int t = threadIdx.x;
  int lane = t & 63;
  int w = t >> 6;
  int lmod = lane & 31, lhalf = lane >> 5;
  int bid = blockIdx.x;
  int lid = (bid & 7) * 1024 + (bid >> 3);
  int rbase = (lid >> 5) * 64;
  int cbase = (lid & 31) * 512;
  int cw = cbase + w * 64;

  floatx16 acc[2][2] = {};
#pragma unroll
  for (int kc = 0; kc < 4; ++kc) {
    int ko = kc * 16 + lhalf * 8;
    half8v a0 = *(const half8v*)&zh[(size_t)(rbase + lmod) * 64 + ko];
    half8v a1 = *(const half8v*)&zh[(size_t)(rbase + 32 + lmod) * 64 + ko];
    half8v b0 = *(const half8v*)&zh[(size_t)(cw + lmod) * 64 + ko];
    half8v b1 = *(const half8v*)&zh[(size_t)(cw + 32 + lmod) * 64 + ko];
    acc[0][0] = MFMA16(a0, b0, acc[0][0]);
    acc[0][1] = MFMA16(a0, b1, acc[0][1]);
    acc[1][0] = MFMA16(a1, b0, acc[1][0]);
    acc[1][1] = MFMA16(a1, b1, acc[1][1]);
  }

#pragma unroll
  for (int band = 0; band < 2; ++band) {
    if (band) __syncthreads();
#pragma unroll
    for (int ct = 0; ct < 2; ++ct) {
#pragma unroll
      for (int reg = 0; reg < 16; ++reg) {
        int r = (reg & 3) + 8 * (reg >> 2) + 4 * lhalf;
        lds[r][w * 64 + ct * 32 + lmod] = acc[band][ct][reg];
      }
    }
    __syncthreads();
#pragma unroll
    for (int j = 0; j < 4; ++j) {
      int row = j * 8 + w;
      int col = lane * 4;
      floatx4 v0 = *(const floatx4*)&lds[row][col];
      floatx4 sg0;
      sg0.x = __builtin_amdgcn_rcpf(1.0f + __expf(-v0.x));
      sg0.y = __builtin_amdgcn_rcpf(1.0f + __expf(-v0.y));
      sg0.z = __builtin_amdgcn_rcpf(1.0f + __expf(-v0.z));
      sg0.w = __builtin_amdgcn_rcpf(1.0f + __expf(-v0.w));
      size_t addr = (size_t)(rbase + band * 32 + row) * N_NODES + cbase + col;
      __builtin_nontemporal_store(sg0, (floatx4*)&out[addr]);
      floatx4 v1 = *(const floatx4*)&lds[row][256 + col];
      floatx4 sg1;
      sg1.x = __builtin_amdgcn_rcpf(1.0f + __expf(-v1.x));
      sg1.y = __builtin_amdgcn_rcpf(1.0f + __expf(-v1.y));
      sg1.z = __builtin_amdgcn_rcpf(1.0f + __expf(-v1.z));
      sg1.w = __builtin_amdgcn_rcpf(1.0f + __expf(-v1.w));
      __builtin_nontemporal_store(sg1, (floatx4*)&out[addr + 256]);
    }
  }
}

// ---------------- launch ----------------

extern "C" void kernel_launch(void* const* d_in, const int* in_sizes, int n_in,
                              void* d_out, int out_size, void* d_ws, size_t ws_size,
                              hipStream_t stream) {
  const float* x = (const float*)d_in[0];
  const float* W_l1 = (const float*)d_in[1];
  const float* W_r1 = (const float*)d_in[2];
  const float* b1 = (const float*)d_in[3];
  const float* W_l2 = (const float*)d_in[4];
  const float* W_r2 = (const float*)d_in[5];
  const float* b2 = (const float*)d_in[6];
  const float* W_lin = (const float*)d_in[7];
  const float* b_lin = (const float*)d_in[8];
  const int* edge = (const int*)d_in[9];
  const int* esrc = edge;
  const int* edst = edge + N_EDGES;

  int* deg = (int*)d_ws;
  int* row_ptr = deg + 16384;
  int* cursor = row_ptr + 16448;
  float* deg_inv = (float*)(cursor + 16384);
  int* col_idx = (int*)(deg_inv + 16384);
  _Float16* xh = (_Float16*)(col_idx + N_EDGES);
  _Float16* hh = xh + (size_t)N_NODES * 128;
  _Float16* aggh = hh + (size_t)N_NODES * 128;
  _Float16* zh = aggh + (size_t)N_NODES * 128;
  _Float16* Wl1t = zh + (size_t)N_NODES * 64;
  _Float16* Wr1t = Wl1t + 16384;
  _Float16* Wl2t = Wr1t + 16384;
  _Float16* Wr2t = Wl2t + 8192;
  _Float16* Wlint = Wr2t + 8192;

  float* A = (float*)d_out;
  float* z = A + (size_t)N_NODES * N_NODES;
  float* xo = z + (size_t)N_NODES * 64;

  (void)hipMemsetAsync(deg, 0, N_NODES * sizeof(int), stream);
  hist_prep_kernel<<<3077, 256, 0, stream>>>(edst, deg, x, xh,
                                             W_l1, W_r1, W_l2, W_r2, W_lin,
                                             Wl1t, Wr1t, Wl2t, Wr2t, Wlint);
  scan_kernel<<<1, 1024, 0, stream>>>(deg, row_ptr, cursor, deg_inv);
  scatter_kernel<<<N_EDGES / 256, 256, 0, stream>>>(esrc, edst, cursor, col_idx);

  aggregate_f16_kernel<<<N_NODES / 8, 512, 0, stream>>>(xh, row_ptr, col_idx, deg_inv, aggh);
  sage1_mfma_kernel<<<N_NODES / 64, 256, 0, stream>>>(aggh, xh, Wl1t, Wr1t, b1, hh);
  aggregate_f16_kernel<<<N_NODES / 8, 512, 0, stream>>>(hh, row_ptr, col_idx, deg_inv, aggh);
  sage2_fused_kernel<<<N_NODES / 64, 256, 0, stream>>>(aggh, hh, Wl2t, Wr2t, b2,
                                                       Wlint, b_lin, z, zh, xo);

  apred_kernel<<<8192, 512, 0, stream>>>(zh, A);
}